// Round 5
// baseline (1169.706 us; speedup 1.0000x reference)
//
#include <hip/hip_runtime.h>
#include <hip/hip_bf16.h>
#include <math.h>

#define N_NODES 100000
#define N_EDGES 3200000
#define NFEAT 512
#define NHID 256
#define NCLASS 40
#define LDP 40    // padded LDS row stride in bf16 elems
#define NB 1024   // CSR buckets
#define RPB 98    // rows per bucket (98*1024 >= 100000)

typedef short bf16x8 __attribute__((ext_vector_type(8)));
typedef float f32x4 __attribute__((ext_vector_type(4)));
typedef unsigned long long u64;

__device__ __forceinline__ unsigned short f2bf(float f) {
    unsigned int u = __builtin_bit_cast(unsigned int, f);
    u += 0x7fffu + ((u >> 16) & 1u);           // round-to-nearest-even
    return (unsigned short)(u >> 16);
}
__device__ __forceinline__ float bflo(unsigned int u) { return __builtin_bit_cast(float, u << 16); }
__device__ __forceinline__ float bfhi(unsigned int u) { return __builtin_bit_cast(float, u & 0xffff0000u); }
__device__ __forceinline__ unsigned int ecol_of(u64 ev) { return (unsigned int)(ev & 0xffffffffu); }
__device__ __forceinline__ float eval_of(u64 ev) { return __builtin_bit_cast(float, (unsigned int)(ev >> 32)); }

// ---------------- CSR build (bucketed) ----------------
// Pass 1: bucket histogram, LDS-privatized
__global__ __launch_bounds__(256) void k_bhist(const int* __restrict__ erow, int* __restrict__ bcount) {
    __shared__ int lh[NB];
    int t = threadIdx.x;
    for (int i = t; i < NB; i += 256) lh[i] = 0;
    __syncthreads();
    for (int e = blockIdx.x * 256 + t; e < N_EDGES; e += 256 * 256)
        atomicAdd(&lh[erow[e] / RPB], 1);
    __syncthreads();
    for (int i = t; i < NB; i += 256)
        if (lh[i]) atomicAdd(&bcount[i], lh[i]);
}

// Pass 2: exclusive scan of 1024 bucket counts (single block), init cursors
__global__ __launch_bounds__(256) void k_bscan(const int* __restrict__ bcount,
                                               int* __restrict__ bucketptr, int* __restrict__ bcursor) {
    __shared__ int sd[256];
    int t = threadIdx.x;
    int base = t * 4;
    int v0 = bcount[base + 0];
    int v1 = bcount[base + 1];
    int v2 = bcount[base + 2];
    int v3 = bcount[base + 3];
    int s = v0 + v1 + v2 + v3;
    sd[t] = s;
    __syncthreads();
    for (int off = 1; off < 256; off <<= 1) {
        int x = (t >= off) ? sd[t - off] : 0;
        __syncthreads();
        sd[t] += x;
        __syncthreads();
    }
    int excl = sd[t] - s;
    bucketptr[base + 0] = excl;              bcursor[base + 0] = excl;
    bucketptr[base + 1] = excl + v0;         bcursor[base + 1] = excl + v0;
    bucketptr[base + 2] = excl + v0 + v1;    bcursor[base + 2] = excl + v0 + v1;
    bucketptr[base + 3] = excl + v0 + v1 + v2; bcursor[base + 3] = excl + v0 + v1 + v2;
    if (t == 255) bucketptr[NB] = sd[255];
}

// Pass 3: append edges into bucket regions (clustered writes)
// brec: lo32 = val bits, hi32 = col | (rowlocal << 17)
__global__ __launch_bounds__(256) void k_bscatter(const int* __restrict__ erow, const int* __restrict__ ecol,
                                                  const float* __restrict__ eval_, int* __restrict__ bcursor,
                                                  u64* __restrict__ brec) {
    int e = blockIdx.x * 256 + threadIdx.x;
    if (e >= N_EDGES) return;
    int r = erow[e];
    int b = r / RPB;
    int rl = r - b * RPB;
    int pos = atomicAdd(&bcursor[b], 1);
    unsigned int hi = (unsigned int)ecol[e] | ((unsigned int)rl << 17);
    u64 rec = (u64)__builtin_bit_cast(unsigned int, eval_[e]) | ((u64)hi << 32);
    brec[pos] = rec;
}

// Pass 4: per-bucket fine sort -> final pedge {lo=col, hi=valbits} + rowptr
__global__ __launch_bounds__(256) void k_bsort(const int* __restrict__ bucketptr,
                                               const u64* __restrict__ brec,
                                               u64* __restrict__ pedge, int* __restrict__ rowptr) {
    __shared__ int lcnt[RPB];
    __shared__ int lcur[RPB];
    __shared__ int sc[128];
    const int b = blockIdx.x;
    const int t = threadIdx.x;
    const int beg = bucketptr[b], end = bucketptr[b + 1];
    const int n = end - beg;
    const int rstart = b * RPB;
    for (int i = t; i < RPB; i += 256) lcnt[i] = 0;
    __syncthreads();
    for (int i = t; i < n; i += 256) {
        int rl = (int)((brec[beg + i] >> 49) & 0x7f);
        atomicAdd(&lcnt[rl], 1);
    }
    __syncthreads();
    if (t < 128) sc[t] = (t < RPB) ? lcnt[t] : 0;
    __syncthreads();
    for (int off = 1; off < 128; off <<= 1) {
        int add = (t < 128 && t >= off) ? sc[t - off] : 0;
        __syncthreads();
        if (t < 128) sc[t] += add;
        __syncthreads();
    }
    if (t < RPB) {
        int ex = sc[t] - lcnt[t];
        lcur[t] = ex;
        int row = rstart + t;
        if (row < N_NODES) rowptr[row] = beg + ex;
    }
    if (b == NB - 1 && t == 0) rowptr[N_NODES] = N_EDGES;
    __syncthreads();
    for (int i = t; i < n; i += 256) {
        u64 rec = brec[beg + i];
        int rl = (int)((rec >> 49) & 0x7f);
        int pos = atomicAdd(&lcur[rl], 1);
        unsigned int col = (unsigned int)(rec >> 32) & 0x1ffffu;
        unsigned int valbits = (unsigned int)(rec & 0xffffffffu);
        pedge[beg + pos] = (u64)col | ((u64)valbits << 32);
    }
}

// ---------------- weight transpose + bf16 convert ----------------
__global__ void k_w1t(const float* __restrict__ W1, unsigned short* __restrict__ W1T) {
    int i = blockIdx.x * 256 + threadIdx.x;   // NHID*NFEAT
    int nn = i >> 9, k = i & 511;
    W1T[i] = f2bf(W1[k * NHID + nn]);
}
__global__ void k_w2t(const float* __restrict__ W2, unsigned short* __restrict__ W2T) {
    int i = blockIdx.x * 256 + threadIdx.x;   // 64*NHID
    int nn = i >> 8, k = i & 255;
    W2T[i] = (nn < NCLASS) ? f2bf(W2[k * NCLASS + nn]) : (unsigned short)0;
}

// ---------------- GEMM1: support[row][256] = bf16(x) @ bf16(W1) ----------------
__global__ __launch_bounds__(512) void k_gemm1(const float* __restrict__ X,
                                               const unsigned short* __restrict__ W1T,
                                               unsigned short* __restrict__ support) {
    __shared__ unsigned short As[128 * LDP];
    __shared__ unsigned short Bs[256 * LDP];
    const int t = threadIdx.x;
    const int lane = t & 63;
    const int w = t >> 6;
    const int wm = w >> 2, wn = w & 3;
    const int l15 = lane & 15, l4 = lane >> 4;
    const int bm = blockIdx.x;

    f32x4 acc[4][4];
#pragma unroll
    for (int m = 0; m < 4; ++m)
#pragma unroll
        for (int n = 0; n < 4; ++n) acc[m][n] = (f32x4){0.f, 0.f, 0.f, 0.f};

    const int arow = t >> 2, aq = t & 3;
    const long growA = (long)bm * 128 + arow;
    const bool avalid = growA < N_NODES;
    const float* xsrc = X + growA * NFEAT + aq * 8;
    unsigned short* adst = &As[arow * LDP + aq * 8];
    const int brow = t >> 1, bhalf = t & 1;
    const unsigned short* bsrc = W1T + (long)brow * NFEAT + bhalf * 16;
    unsigned short* bdst = &Bs[brow * LDP + bhalf * 16];

    for (int kt = 0; kt < NFEAT; kt += 32) {
        union { float4 v4[2]; float f[8]; } a;
        if (avalid) {
            a.v4[0] = *(const float4*)(xsrc + kt + 0);
            a.v4[1] = *(const float4*)(xsrc + kt + 4);
        } else {
            a.v4[0] = make_float4(0.f, 0.f, 0.f, 0.f);
            a.v4[1] = make_float4(0.f, 0.f, 0.f, 0.f);
        }
        union { uint4 q; unsigned short us[8]; } u;
#pragma unroll
        for (int j = 0; j < 8; ++j) u.us[j] = f2bf(a.f[j]);
        uint4 b0 = *(const uint4*)(bsrc + kt);
        uint4 b1v = *(const uint4*)(bsrc + kt + 8);
        *(uint4*)(adst) = u.q;
        *(uint4*)(bdst) = b0;
        *(uint4*)(bdst + 8) = b1v;
        __syncthreads();

        bf16x8 afr[4], bfr[4];
#pragma unroll
        for (int m = 0; m < 4; ++m)
            afr[m] = *(const bf16x8*)&As[(wm * 64 + m * 16 + l15) * LDP + l4 * 8];
#pragma unroll
        for (int n = 0; n < 4; ++n)
            bfr[n] = *(const bf16x8*)&Bs[(wn * 64 + n * 16 + l15) * LDP + l4 * 8];
#pragma unroll
        for (int m = 0; m < 4; ++m)
#pragma unroll
            for (int n = 0; n < 4; ++n)
                acc[m][n] = __builtin_amdgcn_mfma_f32_16x16x32_bf16(bfr[n], afr[m], acc[m][n], 0, 0, 0);
        __syncthreads();
    }
#pragma unroll
    for (int m = 0; m < 4; ++m) {
        long row = (long)bm * 128 + wm * 64 + m * 16 + l15;
        if (row < N_NODES) {
#pragma unroll
            for (int n = 0; n < 4; ++n) {
                int colb = wn * 64 + n * 16 + l4 * 4;
                ushort4 o;
                o.x = f2bf(acc[m][n][0]);
                o.y = f2bf(acc[m][n][1]);
                o.z = f2bf(acc[m][n][2]);
                o.w = f2bf(acc[m][n][3]);
                *(ushort4*)&support[(size_t)row * NHID + colb] = o;
            }
        }
    }
}

// ---------------- SpMM1 + bias + ReLU -> h (bf16). one wave per row, 4-way MLP ----------------
__global__ __launch_bounds__(256) void k_spmm1(const int* __restrict__ rowptr,
                                               const u64* __restrict__ pedge,
                                               const unsigned short* __restrict__ support,
                                               const float* __restrict__ b1,
                                               unsigned short* __restrict__ h) {
    int wrow = (blockIdx.x * 256 + threadIdx.x) >> 6;
    int lane = threadIdx.x & 63;
    if (wrow >= N_NODES) return;
    int beg = rowptr[wrow], end = rowptr[wrow + 1];
    float a0 = 0.f, a1 = 0.f, a2 = 0.f, a3 = 0.f;
    const int c4 = lane * 4;
    int e = beg;
    for (; e + 4 <= end; e += 4) {
        u64 ev0 = __builtin_nontemporal_load(&pedge[e + 0]);
        u64 ev1 = __builtin_nontemporal_load(&pedge[e + 1]);
        u64 ev2 = __builtin_nontemporal_load(&pedge[e + 2]);
        u64 ev3 = __builtin_nontemporal_load(&pedge[e + 3]);
        uint2 g0 = *(const uint2*)&support[(size_t)ecol_of(ev0) * NHID + c4];
        uint2 g1 = *(const uint2*)&support[(size_t)ecol_of(ev1) * NHID + c4];
        uint2 g2 = *(const uint2*)&support[(size_t)ecol_of(ev2) * NHID + c4];
        uint2 g3 = *(const uint2*)&support[(size_t)ecol_of(ev3) * NHID + c4];
        float v0 = eval_of(ev0);
        float v1 = eval_of(ev1);
        float v2 = eval_of(ev2);
        float v3 = eval_of(ev3);
        a0 = fmaf(v0, bflo(g0.x), a0); a1 = fmaf(v0, bfhi(g0.x), a1);
        a2 = fmaf(v0, bflo(g0.y), a2); a3 = fmaf(v0, bfhi(g0.y), a3);
        a0 = fmaf(v1, bflo(g1.x), a0); a1 = fmaf(v1, bfhi(g1.x), a1);
        a2 = fmaf(v1, bflo(g1.y), a2); a3 = fmaf(v1, bfhi(g1.y), a3);
        a0 = fmaf(v2, bflo(g2.x), a0); a1 = fmaf(v2, bfhi(g2.x), a1);
        a2 = fmaf(v2, bflo(g2.y), a2); a3 = fmaf(v2, bfhi(g2.y), a3);
        a0 = fmaf(v3, bflo(g3.x), a0); a1 = fmaf(v3, bfhi(g3.x), a1);
        a2 = fmaf(v3, bflo(g3.y), a2); a3 = fmaf(v3, bfhi(g3.y), a3);
    }
    for (; e < end; ++e) {
        u64 ev = __builtin_nontemporal_load(&pedge[e]);
        float v = eval_of(ev);
        uint2 g = *(const uint2*)&support[(size_t)ecol_of(ev) * NHID + c4];
        a0 = fmaf(v, bflo(g.x), a0); a1 = fmaf(v, bfhi(g.x), a1);
        a2 = fmaf(v, bflo(g.y), a2); a3 = fmaf(v, bfhi(g.y), a3);
    }
    float4 bb = *(const float4*)&b1[c4];
    a0 = fmaxf(a0 + bb.x, 0.f);
    a1 = fmaxf(a1 + bb.y, 0.f);
    a2 = fmaxf(a2 + bb.z, 0.f);
    a3 = fmaxf(a3 + bb.w, 0.f);
    ushort4 o;
    o.x = f2bf(a0); o.y = f2bf(a1); o.z = f2bf(a2); o.w = f2bf(a3);
    *(ushort4*)&h[(size_t)wrow * NHID + c4] = o;
}

// ---------------- GEMM2: logits2[row][40] = h @ W2 (fp32 out) ----------------
__global__ __launch_bounds__(256) void k_gemm2(const unsigned short* __restrict__ H,
                                               const unsigned short* __restrict__ W2T,
                                               float* __restrict__ logits2) {
    __shared__ unsigned short As[128 * LDP];
    __shared__ unsigned short Bs[64 * LDP];
    const int t = threadIdx.x;
    const int lane = t & 63;
    const int w = t >> 6;
    const int wm = w >> 1, wn = w & 1;
    const int l15 = lane & 15, l4 = lane >> 4;
    const int bm = blockIdx.x;

    f32x4 acc[4][2];
#pragma unroll
    for (int m = 0; m < 4; ++m)
#pragma unroll
        for (int n = 0; n < 2; ++n) acc[m][n] = (f32x4){0.f, 0.f, 0.f, 0.f};

    const int srow = t >> 1, shalf = t & 1;
    const long grow = (long)bm * 128 + srow;
    const bool avalid = grow < N_NODES;
    const unsigned short* asrc = H + grow * NHID + shalf * 16;
    const int bn2 = t >> 2, bq = t & 3;
    const unsigned short* bsrc = W2T + bn2 * NHID + bq * 8;

    for (int kt = 0; kt < NHID; kt += 32) {
        uint4 a0, a1;
        if (avalid) {
            a0 = *(const uint4*)(asrc + kt);
            a1 = *(const uint4*)(asrc + kt + 8);
        } else {
            a0 = make_uint4(0, 0, 0, 0);
            a1 = make_uint4(0, 0, 0, 0);
        }
        uint4 bv = *(const uint4*)(bsrc + kt);
        *(uint4*)&As[srow * LDP + shalf * 16] = a0;
        *(uint4*)&As[srow * LDP + shalf * 16 + 8] = a1;
        *(uint4*)&Bs[bn2 * LDP + bq * 8] = bv;
        __syncthreads();

        bf16x8 afr[4], bfr[2];
#pragma unroll
        for (int m = 0; m < 4; ++m)
            afr[m] = *(const bf16x8*)&As[(wm * 64 + m * 16 + l15) * LDP + l4 * 8];
#pragma unroll
        for (int n = 0; n < 2; ++n)
            bfr[n] = *(const bf16x8*)&Bs[(wn * 32 + n * 16 + l15) * LDP + l4 * 8];
#pragma unroll
        for (int m = 0; m < 4; ++m)
#pragma unroll
            for (int n = 0; n < 2; ++n)
                acc[m][n] = __builtin_amdgcn_mfma_f32_16x16x32_bf16(bfr[n], afr[m], acc[m][n], 0, 0, 0);
        __syncthreads();
    }
#pragma unroll
    for (int m = 0; m < 4; ++m) {
        long row = (long)bm * 128 + wm * 64 + m * 16 + l15;
        if (row < N_NODES) {
#pragma unroll
            for (int n = 0; n < 2; ++n) {
                int colb = wn * 32 + n * 16 + l4 * 4;
                if (colb < NCLASS)
                    *(f32x4*)&logits2[(size_t)row * NCLASS + colb] = acc[m][n];
            }
        }
    }
}

// ---------------- SpMM2 + bias + log_softmax -> out (fp32). one wave per row, 4-way MLP ----------------
__global__ __launch_bounds__(256) void k_spmm2(const int* __restrict__ rowptr,
                                               const u64* __restrict__ pedge,
                                               const float* __restrict__ logits2,
                                               const float* __restrict__ b2, float* __restrict__ out) {
    int wrow = (blockIdx.x * 256 + threadIdx.x) >> 6;
    int lane = threadIdx.x & 63;
    if (wrow >= N_NODES) return;
    int beg = rowptr[wrow], end = rowptr[wrow + 1];
    bool act = lane < NCLASS;
    int colidx = act ? lane : 0;
    float acc = 0.f;
    int e = beg;
    for (; e + 4 <= end; e += 4) {
        u64 ev0 = __builtin_nontemporal_load(&pedge[e + 0]);
        u64 ev1 = __builtin_nontemporal_load(&pedge[e + 1]);
        u64 ev2 = __builtin_nontemporal_load(&pedge[e + 2]);
        u64 ev3 = __builtin_nontemporal_load(&pedge[e + 3]);
        float g0 = logits2[(size_t)ecol_of(ev0) * NCLASS + colidx];
        float g1 = logits2[(size_t)ecol_of(ev1) * NCLASS + colidx];
        float g2 = logits2[(size_t)ecol_of(ev2) * NCLASS + colidx];
        float g3 = logits2[(size_t)ecol_of(ev3) * NCLASS + colidx];
        acc = fmaf(eval_of(ev0), g0, acc);
        acc = fmaf(eval_of(ev1), g1, acc);
        acc = fmaf(eval_of(ev2), g2, acc);
        acc = fmaf(eval_of(ev3), g3, acc);
    }
    for (; e < end; ++e) {
        u64 ev = __builtin_nontemporal_load(&pedge[e]);
        float g = logits2[(size_t)ecol_of(ev) * NCLASS + colidx];
        acc = fmaf(eval_of(ev), g, acc);
    }
    acc += b2[colidx];
    float mv = act ? acc : -INFINITY;
#pragma unroll
    for (int off = 32; off; off >>= 1) mv = fmaxf(mv, __shfl_xor(mv, off, 64));
    float p = act ? __expf(acc - mv) : 0.f;
    float s = p;
#pragma unroll
    for (int off = 32; off; off >>= 1) s += __shfl_xor(s, off, 64);
    if (act) out[(size_t)wrow * NCLASS + lane] = acc - mv - __logf(s);
}

extern "C" void kernel_launch(void* const* d_in, const int* in_sizes, int n_in,
                              void* d_out, int out_size, void* d_ws, size_t ws_size,
                              hipStream_t stream) {
    const float* x    = (const float*)d_in[0];
    const int*   erow = (const int*)d_in[1];
    const int*   ecol = (const int*)d_in[2];
    const float* eval_ = (const float*)d_in[3];
    const float* W1   = (const float*)d_in[4];
    const float* b1   = (const float*)d_in[5];
    const float* W2   = (const float*)d_in[6];
    const float* b2   = (const float*)d_in[7];
    float* out = (float*)d_out;

    char* p = (char*)d_ws;
    auto alloc = [&](size_t b) { char* r = p; p += (b + 255) & ~(size_t)255; return r; };
    int* bcount            = (int*)alloc((size_t)NB * 4);
    int* bucketptr         = (int*)alloc((size_t)(NB + 1) * 4);
    int* bcursor           = (int*)alloc((size_t)NB * 4);
    int* rowptr            = (int*)alloc((size_t)(N_NODES + 1) * 4);
    u64* brec              = (u64*)alloc((size_t)N_EDGES * 8);
    u64* pedge             = (u64*)alloc((size_t)N_EDGES * 8);
    unsigned short* W1T    = (unsigned short*)alloc((size_t)NHID * NFEAT * 2);
    unsigned short* W2T    = (unsigned short*)alloc((size_t)64 * NHID * 2);
    unsigned short* support= (unsigned short*)alloc((size_t)N_NODES * NHID * 2);
    unsigned short* h      = (unsigned short*)alloc((size_t)N_NODES * NHID * 2);
    float* logits2         = (float*)alloc((size_t)N_NODES * NCLASS * 4);

    (void)hipMemsetAsync(bcount, 0, (size_t)NB * 4, stream);
    k_bhist<<<256, 256, 0, stream>>>(erow, bcount);
    k_bscan<<<1, 256, 0, stream>>>(bcount, bucketptr, bcursor);
    k_bscatter<<<(N_EDGES + 255) / 256, 256, 0, stream>>>(erow, ecol, eval_, bcursor, brec);
    k_bsort<<<NB, 256, 0, stream>>>(bucketptr, brec, pedge, rowptr);
    k_w1t<<<(NHID * NFEAT) / 256, 256, 0, stream>>>(W1, W1T);
    k_w2t<<<(64 * NHID) / 256, 256, 0, stream>>>(W2, W2T);
    k_gemm1<<<(N_NODES + 127) / 128, 512, 0, stream>>>(x, W1T, support);
    k_spmm1<<<(N_NODES + 3) / 4, 256, 0, stream>>>(rowptr, pedge, support, b1, h);
    k_gemm2<<<(N_NODES + 127) / 128, 256, 0, stream>>>(h, W2T, logits2);
    k_spmm2<<<(N_NODES + 3) / 4, 256, 0, stream>>>(rowptr, pedge, logits2, b2, out);
}

// Round 6
// 582.542 us; speedup vs baseline: 2.0079x; 2.0079x over previous
//
#include <hip/hip_runtime.h>
#include <hip/hip_bf16.h>
#include <math.h>

#define N_NODES 100000
#define N_EDGES 3200000
#define NFEAT 512
#define NHID 256
#define NCLASS 40
#define LDP 40     // padded LDS row stride in bf16 elems
#define NB1 256    // coarse buckets
#define RPB1 391   // rows per bucket (256*391 = 100096 >= 100000)
#define NBLK 256   // scatter blocks
#define CHUNK 12500 // N_EDGES / NBLK exactly

typedef short bf16x8 __attribute__((ext_vector_type(8)));
typedef float f32x4 __attribute__((ext_vector_type(4)));
typedef unsigned long long u64;

__device__ __forceinline__ unsigned short f2bf(float f) {
    unsigned int u = __builtin_bit_cast(unsigned int, f);
    u += 0x7fffu + ((u >> 16) & 1u);           // round-to-nearest-even
    return (unsigned short)(u >> 16);
}
__device__ __forceinline__ float bflo(unsigned int u) { return __builtin_bit_cast(float, u << 16); }
__device__ __forceinline__ float bfhi(unsigned int u) { return __builtin_bit_cast(float, u & 0xffff0000u); }
__device__ __forceinline__ unsigned int ecol_of(u64 ev) { return (unsigned int)(ev & 0xffffffffu); }
__device__ __forceinline__ float eval_of(u64 ev) { return __builtin_bit_cast(float, (unsigned int)(ev >> 32)); }

// ---------------- CSR build: atomic-free radix (2-level counting sort) ----------------
// Pass A: per-block coarse histogram (deterministic chunking, no global atomics)
__global__ __launch_bounds__(256) void k_histA(const int* __restrict__ erow, int* __restrict__ hist) {
    __shared__ int lh[NB1];
    const int t = threadIdx.x, blk = blockIdx.x;
    lh[t] = 0;
    __syncthreads();
    const int base = blk * CHUNK;
    for (int i = t; i < CHUNK; i += 256)
        atomicAdd(&lh[erow[base + i] / RPB1], 1);
    __syncthreads();
    hist[blk * NB1 + t] = lh[t];
}

// Pass B: offs[blk][b] = exclusive prefix over blocks; bucketptr = scan of totals
__global__ __launch_bounds__(256) void k_scanB(const int* __restrict__ hist,
                                               int* __restrict__ offs, int* __restrict__ bucketptr) {
    __shared__ int sd[256];
    const int b = threadIdx.x;
    int run = 0;
#pragma unroll 8
    for (int blk = 0; blk < NBLK; ++blk) {
        int v = hist[blk * NB1 + b];
        offs[blk * NB1 + b] = run;
        run += v;
    }
    sd[b] = run;
    __syncthreads();
    for (int off = 1; off < 256; off <<= 1) {
        int x = (b >= off) ? sd[b - off] : 0;
        __syncthreads();
        sd[b] += x;
        __syncthreads();
    }
    bucketptr[b] = sd[b] - run;
    if (b == 255) bucketptr[NB1] = sd[255];
}

// Pass C: scatter into bucket-sorted tmp; block's segment bases known exactly.
// tmp rec: bits0-16 col, bits17-25 rowlocal, bits32-63 val
__global__ __launch_bounds__(256) void k_scatC(const int* __restrict__ erow, const int* __restrict__ ecol,
                                               const float* __restrict__ eval_,
                                               const int* __restrict__ offs, const int* __restrict__ bucketptr,
                                               u64* __restrict__ tmp) {
    __shared__ int lbase[NB1];
    __shared__ int lcur[NB1];
    const int t = threadIdx.x, blk = blockIdx.x;
    lbase[t] = bucketptr[t] + offs[blk * NB1 + t];
    lcur[t] = 0;
    __syncthreads();
    const int base = blk * CHUNK;
    for (int i = t; i < CHUNK; i += 256) {
        int r = erow[base + i];
        int c = ecol[base + i];
        unsigned int vb = __builtin_bit_cast(unsigned int, eval_[base + i]);
        int b = r / RPB1;
        int rl = r - b * RPB1;
        int rank = atomicAdd(&lcur[b], 1);
        u64 rec = (u64)((unsigned int)c | ((unsigned int)rl << 17)) | ((u64)vb << 32);
        tmp[lbase[b] + rank] = rec;
    }
}

// Pass D: per-bucket fine sort by row -> pedge {lo32=col, hi32=val} + rowptr
__global__ __launch_bounds__(512) void k_sortD(const int* __restrict__ bucketptr, const u64* __restrict__ tmp,
                                               u64* __restrict__ pedge, int* __restrict__ rowptr) {
    __shared__ int lcnt[512];
    __shared__ int sc[512];
    __shared__ int lcur[512];
    const int b = blockIdx.x, t = threadIdx.x;
    const int beg = bucketptr[b], end = bucketptr[b + 1];
    const int n = end - beg;
    lcnt[t] = 0;
    __syncthreads();
    for (int i = t; i < n; i += 512)
        atomicAdd(&lcnt[(int)((tmp[beg + i] >> 17) & 0x1ff)], 1);
    __syncthreads();
    sc[t] = lcnt[t];
    __syncthreads();
    for (int off = 1; off < 512; off <<= 1) {
        int x = (t >= off) ? sc[t - off] : 0;
        __syncthreads();
        sc[t] += x;
        __syncthreads();
    }
    int excl = sc[t] - lcnt[t];
    lcur[t] = excl;
    if (t < RPB1) {
        int row = b * RPB1 + t;
        if (row < N_NODES) rowptr[row] = beg + excl;
    }
    if (b == NB1 - 1 && t == 0) rowptr[N_NODES] = N_EDGES;
    __syncthreads();
    for (int i = t; i < n; i += 512) {
        u64 rec = tmp[beg + i];
        int rl = (int)((rec >> 17) & 0x1ff);
        int pos = atomicAdd(&lcur[rl], 1);
        pedge[beg + pos] = rec & 0xFFFFFFFF0001FFFFull;
    }
}

// ---------------- weight transpose + bf16 convert ----------------
__global__ void k_w1t(const float* __restrict__ W1, unsigned short* __restrict__ W1T) {
    int i = blockIdx.x * 256 + threadIdx.x;   // NHID*NFEAT
    int nn = i >> 9, k = i & 511;
    W1T[i] = f2bf(W1[k * NHID + nn]);
}
__global__ void k_w2t(const float* __restrict__ W2, unsigned short* __restrict__ W2T) {
    int i = blockIdx.x * 256 + threadIdx.x;   // 64*NHID
    int nn = i >> 8, k = i & 255;
    W2T[i] = (nn < NCLASS) ? f2bf(W2[k * NCLASS + nn]) : (unsigned short)0;
}

// ---------------- GEMM1: support[row][256] = bf16(x) @ bf16(W1) ----------------
__global__ __launch_bounds__(512) void k_gemm1(const float* __restrict__ X,
                                               const unsigned short* __restrict__ W1T,
                                               unsigned short* __restrict__ support) {
    __shared__ unsigned short As[128 * LDP];
    __shared__ unsigned short Bs[256 * LDP];
    const int t = threadIdx.x;
    const int lane = t & 63;
    const int w = t >> 6;
    const int wm = w >> 2, wn = w & 3;
    const int l15 = lane & 15, l4 = lane >> 4;
    const int bm = blockIdx.x;

    f32x4 acc[4][4];
#pragma unroll
    for (int m = 0; m < 4; ++m)
#pragma unroll
        for (int n = 0; n < 4; ++n) acc[m][n] = (f32x4){0.f, 0.f, 0.f, 0.f};

    const int arow = t >> 2, aq = t & 3;
    const long growA = (long)bm * 128 + arow;
    const bool avalid = growA < N_NODES;
    const float* xsrc = X + growA * NFEAT + aq * 8;
    unsigned short* adst = &As[arow * LDP + aq * 8];
    const int brow = t >> 1, bhalf = t & 1;
    const unsigned short* bsrc = W1T + (long)brow * NFEAT + bhalf * 16;
    unsigned short* bdst = &Bs[brow * LDP + bhalf * 16];

    for (int kt = 0; kt < NFEAT; kt += 32) {
        union { float4 v4[2]; float f[8]; } a;
        if (avalid) {
            a.v4[0] = *(const float4*)(xsrc + kt + 0);
            a.v4[1] = *(const float4*)(xsrc + kt + 4);
        } else {
            a.v4[0] = make_float4(0.f, 0.f, 0.f, 0.f);
            a.v4[1] = make_float4(0.f, 0.f, 0.f, 0.f);
        }
        union { uint4 q; unsigned short us[8]; } u;
#pragma unroll
        for (int j = 0; j < 8; ++j) u.us[j] = f2bf(a.f[j]);
        uint4 b0 = *(const uint4*)(bsrc + kt);
        uint4 b1v = *(const uint4*)(bsrc + kt + 8);
        *(uint4*)(adst) = u.q;
        *(uint4*)(bdst) = b0;
        *(uint4*)(bdst + 8) = b1v;
        __syncthreads();

        bf16x8 afr[4], bfr[4];
#pragma unroll
        for (int m = 0; m < 4; ++m)
            afr[m] = *(const bf16x8*)&As[(wm * 64 + m * 16 + l15) * LDP + l4 * 8];
#pragma unroll
        for (int n = 0; n < 4; ++n)
            bfr[n] = *(const bf16x8*)&Bs[(wn * 64 + n * 16 + l15) * LDP + l4 * 8];
#pragma unroll
        for (int m = 0; m < 4; ++m)
#pragma unroll
            for (int n = 0; n < 4; ++n)
                acc[m][n] = __builtin_amdgcn_mfma_f32_16x16x32_bf16(bfr[n], afr[m], acc[m][n], 0, 0, 0);
        __syncthreads();
    }
#pragma unroll
    for (int m = 0; m < 4; ++m) {
        long row = (long)bm * 128 + wm * 64 + m * 16 + l15;
        if (row < N_NODES) {
#pragma unroll
            for (int n = 0; n < 4; ++n) {
                int colb = wn * 64 + n * 16 + l4 * 4;
                ushort4 o;
                o.x = f2bf(acc[m][n][0]);
                o.y = f2bf(acc[m][n][1]);
                o.z = f2bf(acc[m][n][2]);
                o.w = f2bf(acc[m][n][3]);
                *(ushort4*)&support[(size_t)row * NHID + colb] = o;
            }
        }
    }
}

// ---------------- SpMM1 + bias + ReLU -> h (bf16). one wave per row, 4-way MLP ----------------
__global__ __launch_bounds__(256) void k_spmm1(const int* __restrict__ rowptr,
                                               const u64* __restrict__ pedge,
                                               const unsigned short* __restrict__ support,
                                               const float* __restrict__ b1,
                                               unsigned short* __restrict__ h) {
    int wrow = (blockIdx.x * 256 + threadIdx.x) >> 6;
    int lane = threadIdx.x & 63;
    if (wrow >= N_NODES) return;
    int beg = rowptr[wrow], end = rowptr[wrow + 1];
    float a0 = 0.f, a1 = 0.f, a2 = 0.f, a3 = 0.f;
    const int c4 = lane * 4;
    int e = beg;
    for (; e + 4 <= end; e += 4) {
        u64 ev0 = __builtin_nontemporal_load(&pedge[e + 0]);
        u64 ev1 = __builtin_nontemporal_load(&pedge[e + 1]);
        u64 ev2 = __builtin_nontemporal_load(&pedge[e + 2]);
        u64 ev3 = __builtin_nontemporal_load(&pedge[e + 3]);
        uint2 g0 = *(const uint2*)&support[(size_t)ecol_of(ev0) * NHID + c4];
        uint2 g1 = *(const uint2*)&support[(size_t)ecol_of(ev1) * NHID + c4];
        uint2 g2 = *(const uint2*)&support[(size_t)ecol_of(ev2) * NHID + c4];
        uint2 g3 = *(const uint2*)&support[(size_t)ecol_of(ev3) * NHID + c4];
        float v0 = eval_of(ev0);
        float v1 = eval_of(ev1);
        float v2 = eval_of(ev2);
        float v3 = eval_of(ev3);
        a0 = fmaf(v0, bflo(g0.x), a0); a1 = fmaf(v0, bfhi(g0.x), a1);
        a2 = fmaf(v0, bflo(g0.y), a2); a3 = fmaf(v0, bfhi(g0.y), a3);
        a0 = fmaf(v1, bflo(g1.x), a0); a1 = fmaf(v1, bfhi(g1.x), a1);
        a2 = fmaf(v1, bflo(g1.y), a2); a3 = fmaf(v1, bfhi(g1.y), a3);
        a0 = fmaf(v2, bflo(g2.x), a0); a1 = fmaf(v2, bfhi(g2.x), a1);
        a2 = fmaf(v2, bflo(g2.y), a2); a3 = fmaf(v2, bfhi(g2.y), a3);
        a0 = fmaf(v3, bflo(g3.x), a0); a1 = fmaf(v3, bfhi(g3.x), a1);
        a2 = fmaf(v3, bflo(g3.y), a2); a3 = fmaf(v3, bfhi(g3.y), a3);
    }
    for (; e < end; ++e) {
        u64 ev = __builtin_nontemporal_load(&pedge[e]);
        float v = eval_of(ev);
        uint2 g = *(const uint2*)&support[(size_t)ecol_of(ev) * NHID + c4];
        a0 = fmaf(v, bflo(g.x), a0); a1 = fmaf(v, bfhi(g.x), a1);
        a2 = fmaf(v, bflo(g.y), a2); a3 = fmaf(v, bfhi(g.y), a3);
    }
    float4 bb = *(const float4*)&b1[c4];
    a0 = fmaxf(a0 + bb.x, 0.f);
    a1 = fmaxf(a1 + bb.y, 0.f);
    a2 = fmaxf(a2 + bb.z, 0.f);
    a3 = fmaxf(a3 + bb.w, 0.f);
    ushort4 o;
    o.x = f2bf(a0); o.y = f2bf(a1); o.z = f2bf(a2); o.w = f2bf(a3);
    *(ushort4*)&h[(size_t)wrow * NHID + c4] = o;
}

// ---------------- GEMM2: logits2[row][40] = h @ W2 (fp32 out) ----------------
__global__ __launch_bounds__(256) void k_gemm2(const unsigned short* __restrict__ H,
                                               const unsigned short* __restrict__ W2T,
                                               float* __restrict__ logits2) {
    __shared__ unsigned short As[128 * LDP];
    __shared__ unsigned short Bs[64 * LDP];
    const int t = threadIdx.x;
    const int lane = t & 63;
    const int w = t >> 6;
    const int wm = w >> 1, wn = w & 1;
    const int l15 = lane & 15, l4 = lane >> 4;
    const int bm = blockIdx.x;

    f32x4 acc[4][2];
#pragma unroll
    for (int m = 0; m < 4; ++m)
#pragma unroll
        for (int n = 0; n < 2; ++n) acc[m][n] = (f32x4){0.f, 0.f, 0.f, 0.f};

    const int srow = t >> 1, shalf = t & 1;
    const long grow = (long)bm * 128 + srow;
    const bool avalid = grow < N_NODES;
    const unsigned short* asrc = H + grow * NHID + shalf * 16;
    const int bn2 = t >> 2, bq = t & 3;
    const unsigned short* bsrc = W2T + bn2 * NHID + bq * 8;

    for (int kt = 0; kt < NHID; kt += 32) {
        uint4 a0, a1;
        if (avalid) {
            a0 = *(const uint4*)(asrc + kt);
            a1 = *(const uint4*)(asrc + kt + 8);
        } else {
            a0 = make_uint4(0, 0, 0, 0);
            a1 = make_uint4(0, 0, 0, 0);
        }
        uint4 bv = *(const uint4*)(bsrc + kt);
        *(uint4*)&As[srow * LDP + shalf * 16] = a0;
        *(uint4*)&As[srow * LDP + shalf * 16 + 8] = a1;
        *(uint4*)&Bs[bn2 * LDP + bq * 8] = bv;
        __syncthreads();

        bf16x8 afr[4], bfr[2];
#pragma unroll
        for (int m = 0; m < 4; ++m)
            afr[m] = *(const bf16x8*)&As[(wm * 64 + m * 16 + l15) * LDP + l4 * 8];
#pragma unroll
        for (int n = 0; n < 2; ++n)
            bfr[n] = *(const bf16x8*)&Bs[(wn * 32 + n * 16 + l15) * LDP + l4 * 8];
#pragma unroll
        for (int m = 0; m < 4; ++m)
#pragma unroll
            for (int n = 0; n < 2; ++n)
                acc[m][n] = __builtin_amdgcn_mfma_f32_16x16x32_bf16(bfr[n], afr[m], acc[m][n], 0, 0, 0);
        __syncthreads();
    }
#pragma unroll
    for (int m = 0; m < 4; ++m) {
        long row = (long)bm * 128 + wm * 64 + m * 16 + l15;
        if (row < N_NODES) {
#pragma unroll
            for (int n = 0; n < 2; ++n) {
                int colb = wn * 32 + n * 16 + l4 * 4;
                if (colb < NCLASS)
                    *(f32x4*)&logits2[(size_t)row * NCLASS + colb] = acc[m][n];
            }
        }
    }
}

// ---------------- SpMM2 + bias + log_softmax -> out (fp32). one wave per row, 4-way MLP ----------------
__global__ __launch_bounds__(256) void k_spmm2(const int* __restrict__ rowptr,
                                               const u64* __restrict__ pedge,
                                               const float* __restrict__ logits2,
                                               const float* __restrict__ b2, float* __restrict__ out) {
    int wrow = (blockIdx.x * 256 + threadIdx.x) >> 6;
    int lane = threadIdx.x & 63;
    if (wrow >= N_NODES) return;
    int beg = rowptr[wrow], end = rowptr[wrow + 1];
    bool act = lane < NCLASS;
    int colidx = act ? lane : 0;
    float acc = 0.f;
    int e = beg;
    for (; e + 4 <= end; e += 4) {
        u64 ev0 = __builtin_nontemporal_load(&pedge[e + 0]);
        u64 ev1 = __builtin_nontemporal_load(&pedge[e + 1]);
        u64 ev2 = __builtin_nontemporal_load(&pedge[e + 2]);
        u64 ev3 = __builtin_nontemporal_load(&pedge[e + 3]);
        float g0 = logits2[(size_t)ecol_of(ev0) * NCLASS + colidx];
        float g1 = logits2[(size_t)ecol_of(ev1) * NCLASS + colidx];
        float g2 = logits2[(size_t)ecol_of(ev2) * NCLASS + colidx];
        float g3 = logits2[(size_t)ecol_of(ev3) * NCLASS + colidx];
        acc = fmaf(eval_of(ev0), g0, acc);
        acc = fmaf(eval_of(ev1), g1, acc);
        acc = fmaf(eval_of(ev2), g2, acc);
        acc = fmaf(eval_of(ev3), g3, acc);
    }
    for (; e < end; ++e) {
        u64 ev = __builtin_nontemporal_load(&pedge[e]);
        float g = logits2[(size_t)ecol_of(ev) * NCLASS + colidx];
        acc = fmaf(eval_of(ev), g, acc);
    }
    acc += b2[colidx];
    float mv = act ? acc : -INFINITY;
#pragma unroll
    for (int off = 32; off; off >>= 1) mv = fmaxf(mv, __shfl_xor(mv, off, 64));
    float p = act ? __expf(acc - mv) : 0.f;
    float s = p;
#pragma unroll
    for (int off = 32; off; off >>= 1) s += __shfl_xor(s, off, 64);
    if (act) out[(size_t)wrow * NCLASS + lane] = acc - mv - __logf(s);
}

extern "C" void kernel_launch(void* const* d_in, const int* in_sizes, int n_in,
                              void* d_out, int out_size, void* d_ws, size_t ws_size,
                              hipStream_t stream) {
    const float* x    = (const float*)d_in[0];
    const int*   erow = (const int*)d_in[1];
    const int*   ecol = (const int*)d_in[2];
    const float* eval_ = (const float*)d_in[3];
    const float* W1   = (const float*)d_in[4];
    const float* b1   = (const float*)d_in[5];
    const float* W2   = (const float*)d_in[6];
    const float* b2   = (const float*)d_in[7];
    float* out = (float*)d_out;

    char* p = (char*)d_ws;
    auto alloc = [&](size_t b) { char* r = p; p += (b + 255) & ~(size_t)255; return r; };
    int* hist              = (int*)alloc((size_t)NBLK * NB1 * 4);
    int* offs              = (int*)alloc((size_t)NBLK * NB1 * 4);
    int* bucketptr         = (int*)alloc((size_t)(NB1 + 1) * 4);
    int* rowptr            = (int*)alloc((size_t)(N_NODES + 1) * 4);
    u64* tmp               = (u64*)alloc((size_t)N_EDGES * 8);
    u64* pedge             = (u64*)alloc((size_t)N_EDGES * 8);
    unsigned short* W1T    = (unsigned short*)alloc((size_t)NHID * NFEAT * 2);
    unsigned short* W2T    = (unsigned short*)alloc((size_t)64 * NHID * 2);
    unsigned short* support= (unsigned short*)alloc((size_t)N_NODES * NHID * 2);
    unsigned short* h      = (unsigned short*)alloc((size_t)N_NODES * NHID * 2);
    float* logits2         = (float*)alloc((size_t)N_NODES * NCLASS * 4);

    k_histA<<<NBLK, 256, 0, stream>>>(erow, hist);
    k_scanB<<<1, 256, 0, stream>>>(hist, offs, bucketptr);
    k_scatC<<<NBLK, 256, 0, stream>>>(erow, ecol, eval_, offs, bucketptr, tmp);
    k_sortD<<<NB1, 512, 0, stream>>>(bucketptr, tmp, pedge, rowptr);
    k_w1t<<<(NHID * NFEAT) / 256, 256, 0, stream>>>(W1, W1T);
    k_w2t<<<(64 * NHID) / 256, 256, 0, stream>>>(W2, W2T);
    k_gemm1<<<(N_NODES + 127) / 128, 512, 0, stream>>>(x, W1T, support);
    k_spmm1<<<(N_NODES + 3) / 4, 256, 0, stream>>>(rowptr, pedge, support, b1, h);
    k_gemm2<<<(N_NODES + 127) / 128, 256, 0, stream>>>(h, W2T, logits2);
    k_spmm2<<<(N_NODES + 3) / 4, 256, 0, stream>>>(rowptr, pedge, logits2, b2, out);
}

// Round 7
// 547.108 us; speedup vs baseline: 2.1380x; 1.0648x over previous
//
#include <hip/hip_runtime.h>
#include <hip/hip_bf16.h>
#include <math.h>

#define N_NODES 100000
#define N_EDGES 3200000
#define NFEAT 512
#define NHID 256
#define NCLASS 40
#define LDP 40     // padded LDS row stride in bf16 elems
#define NB1 256    // coarse buckets
#define RPB1 391   // rows per bucket (256*391 = 100096 >= 100000)
#define NBLK 256   // scatter blocks
#define CHUNK 12500 // N_EDGES / NBLK exactly

typedef short bf16x8 __attribute__((ext_vector_type(8)));
typedef float f32x4 __attribute__((ext_vector_type(4)));
typedef unsigned long long u64;

__device__ __forceinline__ unsigned short f2bf(float f) {
    unsigned int u = __builtin_bit_cast(unsigned int, f);
    u += 0x7fffu + ((u >> 16) & 1u);           // round-to-nearest-even
    return (unsigned short)(u >> 16);
}
__device__ __forceinline__ float bflo(unsigned int u) { return __builtin_bit_cast(float, u << 16); }
__device__ __forceinline__ float bfhi(unsigned int u) { return __builtin_bit_cast(float, u & 0xffff0000u); }
__device__ __forceinline__ unsigned int ecol_of(u64 ev) { return (unsigned int)(ev & 0xffffffffu); }
__device__ __forceinline__ float eval_of(u64 ev) { return __builtin_bit_cast(float, (unsigned int)(ev >> 32)); }

// ---------------- CSR build: atomic-free radix (2-level counting sort) ----------------
__global__ __launch_bounds__(256) void k_histA(const int* __restrict__ erow, int* __restrict__ hist) {
    __shared__ int lh[NB1];
    const int t = threadIdx.x, blk = blockIdx.x;
    lh[t] = 0;
    __syncthreads();
    const int base = blk * CHUNK;
    for (int i = t; i < CHUNK; i += 256)
        atomicAdd(&lh[erow[base + i] / RPB1], 1);
    __syncthreads();
    hist[blk * NB1 + t] = lh[t];
}

__global__ __launch_bounds__(256) void k_scanB(const int* __restrict__ hist,
                                               int* __restrict__ offs, int* __restrict__ bucketptr) {
    __shared__ int sd[256];
    const int b = threadIdx.x;
    int run = 0;
#pragma unroll 8
    for (int blk = 0; blk < NBLK; ++blk) {
        int v = hist[blk * NB1 + b];
        offs[blk * NB1 + b] = run;
        run += v;
    }
    sd[b] = run;
    __syncthreads();
    for (int off = 1; off < 256; off <<= 1) {
        int x = (b >= off) ? sd[b - off] : 0;
        __syncthreads();
        sd[b] += x;
        __syncthreads();
    }
    bucketptr[b] = sd[b] - run;
    if (b == 255) bucketptr[NB1] = sd[255];
}

__global__ __launch_bounds__(256) void k_scatC(const int* __restrict__ erow, const int* __restrict__ ecol,
                                               const float* __restrict__ eval_,
                                               const int* __restrict__ offs, const int* __restrict__ bucketptr,
                                               u64* __restrict__ tmp) {
    __shared__ int lbase[NB1];
    __shared__ int lcur[NB1];
    const int t = threadIdx.x, blk = blockIdx.x;
    lbase[t] = bucketptr[t] + offs[blk * NB1 + t];
    lcur[t] = 0;
    __syncthreads();
    const int base = blk * CHUNK;
    for (int i = t; i < CHUNK; i += 256) {
        int r = erow[base + i];
        int c = ecol[base + i];
        unsigned int vb = __builtin_bit_cast(unsigned int, eval_[base + i]);
        int b = r / RPB1;
        int rl = r - b * RPB1;
        int rank = atomicAdd(&lcur[b], 1);
        u64 rec = (u64)((unsigned int)c | ((unsigned int)rl << 17)) | ((u64)vb << 32);
        tmp[lbase[b] + rank] = rec;
    }
}

__global__ __launch_bounds__(512) void k_sortD(const int* __restrict__ bucketptr, const u64* __restrict__ tmp,
                                               u64* __restrict__ pedge, int* __restrict__ rowptr) {
    __shared__ int lcnt[512];
    __shared__ int sc[512];
    __shared__ int lcur[512];
    const int b = blockIdx.x, t = threadIdx.x;
    const int beg = bucketptr[b], end = bucketptr[b + 1];
    const int n = end - beg;
    lcnt[t] = 0;
    __syncthreads();
    for (int i = t; i < n; i += 512)
        atomicAdd(&lcnt[(int)((tmp[beg + i] >> 17) & 0x1ff)], 1);
    __syncthreads();
    sc[t] = lcnt[t];
    __syncthreads();
    for (int off = 1; off < 512; off <<= 1) {
        int x = (t >= off) ? sc[t - off] : 0;
        __syncthreads();
        sc[t] += x;
        __syncthreads();
    }
    int excl = sc[t] - lcnt[t];
    lcur[t] = excl;
    if (t < RPB1) {
        int row = b * RPB1 + t;
        if (row < N_NODES) rowptr[row] = beg + excl;
    }
    if (b == NB1 - 1 && t == 0) rowptr[N_NODES] = N_EDGES;
    __syncthreads();
    for (int i = t; i < n; i += 512) {
        u64 rec = tmp[beg + i];
        int rl = (int)((rec >> 17) & 0x1ff);
        int pos = atomicAdd(&lcur[rl], 1);
        pedge[beg + pos] = rec & 0xFFFFFFFF0001FFFFull;
    }
}

// ---------------- weight transpose + bf16 convert ----------------
__global__ void k_w1t(const float* __restrict__ W1, unsigned short* __restrict__ W1T) {
    int i = blockIdx.x * 256 + threadIdx.x;   // NHID*NFEAT
    int nn = i >> 9, k = i & 511;
    W1T[i] = f2bf(W1[k * NHID + nn]);
}
__global__ void k_w2t(const float* __restrict__ W2, unsigned short* __restrict__ W2T) {
    int i = blockIdx.x * 256 + threadIdx.x;   // 64*NHID
    int nn = i >> 8, k = i & 255;
    W2T[i] = (nn < NCLASS) ? f2bf(W2[k * NCLASS + nn]) : (unsigned short)0;
}

// ---------------- GEMM1: support[row][256] = bf16(x) @ bf16(W1) ----------------
__global__ __launch_bounds__(512) void k_gemm1(const float* __restrict__ X,
                                               const unsigned short* __restrict__ W1T,
                                               unsigned short* __restrict__ support) {
    __shared__ unsigned short As[128 * LDP];
    __shared__ unsigned short Bs[256 * LDP];
    const int t = threadIdx.x;
    const int lane = t & 63;
    const int w = t >> 6;
    const int wm = w >> 2, wn = w & 3;
    const int l15 = lane & 15, l4 = lane >> 4;
    const int bm = blockIdx.x;

    f32x4 acc[4][4];
#pragma unroll
    for (int m = 0; m < 4; ++m)
#pragma unroll
        for (int n = 0; n < 4; ++n) acc[m][n] = (f32x4){0.f, 0.f, 0.f, 0.f};

    const int arow = t >> 2, aq = t & 3;
    const long growA = (long)bm * 128 + arow;
    const bool avalid = growA < N_NODES;
    const float* xsrc = X + growA * NFEAT + aq * 8;
    unsigned short* adst = &As[arow * LDP + aq * 8];
    const int brow = t >> 1, bhalf = t & 1;
    const unsigned short* bsrc = W1T + (long)brow * NFEAT + bhalf * 16;
    unsigned short* bdst = &Bs[brow * LDP + bhalf * 16];

    for (int kt = 0; kt < NFEAT; kt += 32) {
        union { float4 v4[2]; float f[8]; } a;
        if (avalid) {
            a.v4[0] = *(const float4*)(xsrc + kt + 0);
            a.v4[1] = *(const float4*)(xsrc + kt + 4);
        } else {
            a.v4[0] = make_float4(0.f, 0.f, 0.f, 0.f);
            a.v4[1] = make_float4(0.f, 0.f, 0.f, 0.f);
        }
        union { uint4 q; unsigned short us[8]; } u;
#pragma unroll
        for (int j = 0; j < 8; ++j) u.us[j] = f2bf(a.f[j]);
        uint4 b0 = *(const uint4*)(bsrc + kt);
        uint4 b1v = *(const uint4*)(bsrc + kt + 8);
        *(uint4*)(adst) = u.q;
        *(uint4*)(bdst) = b0;
        *(uint4*)(bdst + 8) = b1v;
        __syncthreads();

        bf16x8 afr[4], bfr[4];
#pragma unroll
        for (int m = 0; m < 4; ++m)
            afr[m] = *(const bf16x8*)&As[(wm * 64 + m * 16 + l15) * LDP + l4 * 8];
#pragma unroll
        for (int n = 0; n < 4; ++n)
            bfr[n] = *(const bf16x8*)&Bs[(wn * 64 + n * 16 + l15) * LDP + l4 * 8];
#pragma unroll
        for (int m = 0; m < 4; ++m)
#pragma unroll
            for (int n = 0; n < 4; ++n)
                acc[m][n] = __builtin_amdgcn_mfma_f32_16x16x32_bf16(bfr[n], afr[m], acc[m][n], 0, 0, 0);
        __syncthreads();
    }
#pragma unroll
    for (int m = 0; m < 4; ++m) {
        long row = (long)bm * 128 + wm * 64 + m * 16 + l15;
        if (row < N_NODES) {
#pragma unroll
            for (int n = 0; n < 4; ++n) {
                int colb = wn * 64 + n * 16 + l4 * 4;
                ushort4 o;
                o.x = f2bf(acc[m][n][0]);
                o.y = f2bf(acc[m][n][1]);
                o.z = f2bf(acc[m][n][2]);
                o.w = f2bf(acc[m][n][3]);
                *(ushort4*)&support[(size_t)row * NHID + colb] = o;
            }
        }
    }
}

// ---------------- SpMM1 + bias + ReLU -> h (bf16). one wave per row, 8-way MLP ----------------
__global__ __launch_bounds__(256) void k_spmm1(const int* __restrict__ rowptr,
                                               const u64* __restrict__ pedge,
                                               const unsigned short* __restrict__ support,
                                               const float* __restrict__ b1,
                                               unsigned short* __restrict__ h) {
    int wrow = (blockIdx.x * 256 + threadIdx.x) >> 6;
    int lane = threadIdx.x & 63;
    if (wrow >= N_NODES) return;
    int beg = rowptr[wrow], end = rowptr[wrow + 1];
    float a0 = 0.f, a1 = 0.f, a2 = 0.f, a3 = 0.f;
    const int c4 = lane * 4;
    int e = beg;
    for (; e + 8 <= end; e += 8) {
        u64 ev[8];
#pragma unroll
        for (int j = 0; j < 8; ++j) ev[j] = __builtin_nontemporal_load(&pedge[e + j]);
        uint2 g[8];
#pragma unroll
        for (int j = 0; j < 8; ++j)
            g[j] = *(const uint2*)&support[(size_t)ecol_of(ev[j]) * NHID + c4];
#pragma unroll
        for (int j = 0; j < 8; ++j) {
            float v = eval_of(ev[j]);
            a0 = fmaf(v, bflo(g[j].x), a0); a1 = fmaf(v, bfhi(g[j].x), a1);
            a2 = fmaf(v, bflo(g[j].y), a2); a3 = fmaf(v, bfhi(g[j].y), a3);
        }
    }
    if (e + 4 <= end) {
        u64 ev[4];
#pragma unroll
        for (int j = 0; j < 4; ++j) ev[j] = __builtin_nontemporal_load(&pedge[e + j]);
        uint2 g[4];
#pragma unroll
        for (int j = 0; j < 4; ++j)
            g[j] = *(const uint2*)&support[(size_t)ecol_of(ev[j]) * NHID + c4];
#pragma unroll
        for (int j = 0; j < 4; ++j) {
            float v = eval_of(ev[j]);
            a0 = fmaf(v, bflo(g[j].x), a0); a1 = fmaf(v, bfhi(g[j].x), a1);
            a2 = fmaf(v, bflo(g[j].y), a2); a3 = fmaf(v, bfhi(g[j].y), a3);
        }
        e += 4;
    }
    for (; e < end; ++e) {
        u64 ev = __builtin_nontemporal_load(&pedge[e]);
        float v = eval_of(ev);
        uint2 g = *(const uint2*)&support[(size_t)ecol_of(ev) * NHID + c4];
        a0 = fmaf(v, bflo(g.x), a0); a1 = fmaf(v, bfhi(g.x), a1);
        a2 = fmaf(v, bflo(g.y), a2); a3 = fmaf(v, bfhi(g.y), a3);
    }
    float4 bb = *(const float4*)&b1[c4];
    a0 = fmaxf(a0 + bb.x, 0.f);
    a1 = fmaxf(a1 + bb.y, 0.f);
    a2 = fmaxf(a2 + bb.z, 0.f);
    a3 = fmaxf(a3 + bb.w, 0.f);
    ushort4 o;
    o.x = f2bf(a0); o.y = f2bf(a1); o.z = f2bf(a2); o.w = f2bf(a3);
    *(ushort4*)&h[(size_t)wrow * NHID + c4] = o;
}

// ---------------- GEMM2: logits2[row][40] = h @ W2 (fp32 out) ----------------
__global__ __launch_bounds__(256) void k_gemm2(const unsigned short* __restrict__ H,
                                               const unsigned short* __restrict__ W2T,
                                               float* __restrict__ logits2) {
    __shared__ unsigned short As[128 * LDP];
    __shared__ unsigned short Bs[64 * LDP];
    const int t = threadIdx.x;
    const int lane = t & 63;
    const int w = t >> 6;
    const int wm = w >> 1, wn = w & 1;
    const int l15 = lane & 15, l4 = lane >> 4;
    const int bm = blockIdx.x;

    f32x4 acc[4][2];
#pragma unroll
    for (int m = 0; m < 4; ++m)
#pragma unroll
        for (int n = 0; n < 2; ++n) acc[m][n] = (f32x4){0.f, 0.f, 0.f, 0.f};

    const int srow = t >> 1, shalf = t & 1;
    const long grow = (long)bm * 128 + srow;
    const bool avalid = grow < N_NODES;
    const unsigned short* asrc = H + grow * NHID + shalf * 16;
    const int bn2 = t >> 2, bq = t & 3;
    const unsigned short* bsrc = W2T + bn2 * NHID + bq * 8;

    for (int kt = 0; kt < NHID; kt += 32) {
        uint4 a0, a1;
        if (avalid) {
            a0 = *(const uint4*)(asrc + kt);
            a1 = *(const uint4*)(asrc + kt + 8);
        } else {
            a0 = make_uint4(0, 0, 0, 0);
            a1 = make_uint4(0, 0, 0, 0);
        }
        uint4 bv = *(const uint4*)(bsrc + kt);
        *(uint4*)&As[srow * LDP + shalf * 16] = a0;
        *(uint4*)&As[srow * LDP + shalf * 16 + 8] = a1;
        *(uint4*)&Bs[bn2 * LDP + bq * 8] = bv;
        __syncthreads();

        bf16x8 afr[4], bfr[2];
#pragma unroll
        for (int m = 0; m < 4; ++m)
            afr[m] = *(const bf16x8*)&As[(wm * 64 + m * 16 + l15) * LDP + l4 * 8];
#pragma unroll
        for (int n = 0; n < 2; ++n)
            bfr[n] = *(const bf16x8*)&Bs[(wn * 32 + n * 16 + l15) * LDP + l4 * 8];
#pragma unroll
        for (int m = 0; m < 4; ++m)
#pragma unroll
            for (int n = 0; n < 2; ++n)
                acc[m][n] = __builtin_amdgcn_mfma_f32_16x16x32_bf16(bfr[n], afr[m], acc[m][n], 0, 0, 0);
        __syncthreads();
    }
#pragma unroll
    for (int m = 0; m < 4; ++m) {
        long row = (long)bm * 128 + wm * 64 + m * 16 + l15;
        if (row < N_NODES) {
#pragma unroll
            for (int n = 0; n < 2; ++n) {
                int colb = wn * 32 + n * 16 + l4 * 4;
                if (colb < NCLASS)
                    *(f32x4*)&logits2[(size_t)row * NCLASS + colb] = acc[m][n];
            }
        }
    }
}

// ---------------- SpMM2 + bias + log_softmax -> out (fp32). one wave per row, 8-way MLP ----------------
__global__ __launch_bounds__(256) void k_spmm2(const int* __restrict__ rowptr,
                                               const u64* __restrict__ pedge,
                                               const float* __restrict__ logits2,
                                               const float* __restrict__ b2, float* __restrict__ out) {
    int wrow = (blockIdx.x * 256 + threadIdx.x) >> 6;
    int lane = threadIdx.x & 63;
    if (wrow >= N_NODES) return;
    int beg = rowptr[wrow], end = rowptr[wrow + 1];
    bool act = lane < NCLASS;
    int colidx = act ? lane : 0;
    float acc = 0.f;
    int e = beg;
    for (; e + 8 <= end; e += 8) {
        u64 ev[8];
#pragma unroll
        for (int j = 0; j < 8; ++j) ev[j] = __builtin_nontemporal_load(&pedge[e + j]);
        float g[8];
#pragma unroll
        for (int j = 0; j < 8; ++j) g[j] = logits2[(size_t)ecol_of(ev[j]) * NCLASS + colidx];
#pragma unroll
        for (int j = 0; j < 8; ++j) acc = fmaf(eval_of(ev[j]), g[j], acc);
    }
    if (e + 4 <= end) {
        u64 ev[4];
#pragma unroll
        for (int j = 0; j < 4; ++j) ev[j] = __builtin_nontemporal_load(&pedge[e + j]);
        float g[4];
#pragma unroll
        for (int j = 0; j < 4; ++j) g[j] = logits2[(size_t)ecol_of(ev[j]) * NCLASS + colidx];
#pragma unroll
        for (int j = 0; j < 4; ++j) acc = fmaf(eval_of(ev[j]), g[j], acc);
        e += 4;
    }
    for (; e < end; ++e) {
        u64 ev = __builtin_nontemporal_load(&pedge[e]);
        float g = logits2[(size_t)ecol_of(ev) * NCLASS + colidx];
        acc = fmaf(eval_of(ev), g, acc);
    }
    acc += b2[colidx];
    float mv = act ? acc : -INFINITY;
#pragma unroll
    for (int off = 32; off; off >>= 1) mv = fmaxf(mv, __shfl_xor(mv, off, 64));
    float p = act ? __expf(acc - mv) : 0.f;
    float s = p;
#pragma unroll
    for (int off = 32; off; off >>= 1) s += __shfl_xor(s, off, 64);
    if (act) out[(size_t)wrow * NCLASS + lane] = acc - mv - __logf(s);
}

extern "C" void kernel_launch(void* const* d_in, const int* in_sizes, int n_in,
                              void* d_out, int out_size, void* d_ws, size_t ws_size,
                              hipStream_t stream) {
    const float* x    = (const float*)d_in[0];
    const int*   erow = (const int*)d_in[1];
    const int*   ecol = (const int*)d_in[2];
    const float* eval_ = (const float*)d_in[3];
    const float* W1   = (const float*)d_in[4];
    const float* b1   = (const float*)d_in[5];
    const float* W2   = (const float*)d_in[6];
    const float* b2   = (const float*)d_in[7];
    float* out = (float*)d_out;

    char* p = (char*)d_ws;
    auto alloc = [&](size_t b) { char* r = p; p += (b + 255) & ~(size_t)255; return r; };
    int* hist              = (int*)alloc((size_t)NBLK * NB1 * 4);
    int* offs              = (int*)alloc((size_t)NBLK * NB1 * 4);
    int* bucketptr         = (int*)alloc((size_t)(NB1 + 1) * 4);
    int* rowptr            = (int*)alloc((size_t)(N_NODES + 1) * 4);
    u64* tmp               = (u64*)alloc((size_t)N_EDGES * 8);
    u64* pedge             = (u64*)alloc((size_t)N_EDGES * 8);
    unsigned short* W1T    = (unsigned short*)alloc((size_t)NHID * NFEAT * 2);
    unsigned short* W2T    = (unsigned short*)alloc((size_t)64 * NHID * 2);
    unsigned short* support= (unsigned short*)alloc((size_t)N_NODES * NHID * 2);
    unsigned short* h      = (unsigned short*)alloc((size_t)N_NODES * NHID * 2);
    float* logits2         = (float*)alloc((size_t)N_NODES * NCLASS * 4);

    k_histA<<<NBLK, 256, 0, stream>>>(erow, hist);
    k_scanB<<<1, 256, 0, stream>>>(hist, offs, bucketptr);
    k_scatC<<<NBLK, 256, 0, stream>>>(erow, ecol, eval_, offs, bucketptr, tmp);
    k_sortD<<<NB1, 512, 0, stream>>>(bucketptr, tmp, pedge, rowptr);
    k_w1t<<<(NHID * NFEAT) / 256, 256, 0, stream>>>(W1, W1T);
    k_w2t<<<(64 * NHID) / 256, 256, 0, stream>>>(W2, W2T);
    k_gemm1<<<(N_NODES + 127) / 128, 512, 0, stream>>>(x, W1T, support);
    k_spmm1<<<(N_NODES + 3) / 4, 256, 0, stream>>>(rowptr, pedge, support, b1, h);
    k_gemm2<<<(N_NODES + 127) / 128, 256, 0, stream>>>(h, W2T, logits2);
    k_spmm2<<<(N_NODES + 3) / 4, 256, 0, stream>>>(rowptr, pedge, logits2, b2, out);
}

// Round 8
// 459.823 us; speedup vs baseline: 2.5438x; 1.1898x over previous
//
#include <hip/hip_runtime.h>
#include <hip/hip_bf16.h>
#include <math.h>

#define N_NODES 100000
#define N_EDGES 3200000
#define NFEAT 512
#define NHID 256
#define NCLASS 40
#define LDP 40     // padded LDS row stride in bf16 elems
#define NB1 256    // coarse buckets
#define RPB1 391   // rows per bucket (256*391 = 100096 >= 100000)
#define NBLK 256   // scatter blocks
#define CHUNK 12500 // N_EDGES / NBLK exactly

#if __has_builtin(__builtin_amdgcn_cvt_pk_fp8_f32) && __has_builtin(__builtin_amdgcn_cvt_pk_f32_fp8)
#define SUP_FP8 1
#else
#define SUP_FP8 0
#endif

typedef short bf16x8 __attribute__((ext_vector_type(8)));
typedef float f32x4 __attribute__((ext_vector_type(4)));
typedef float f32x2 __attribute__((ext_vector_type(2)));
typedef unsigned long long u64;

__device__ __forceinline__ unsigned short f2bf(float f) {
    unsigned int u = __builtin_bit_cast(unsigned int, f);
    u += 0x7fffu + ((u >> 16) & 1u);           // round-to-nearest-even
    return (unsigned short)(u >> 16);
}
__device__ __forceinline__ float bflo(unsigned int u) { return __builtin_bit_cast(float, u << 16); }
__device__ __forceinline__ float bfhi(unsigned int u) { return __builtin_bit_cast(float, u & 0xffff0000u); }
__device__ __forceinline__ unsigned int ecol_of(u64 ev) { return (unsigned int)(ev & 0xffffffffu); }
__device__ __forceinline__ float eval_of(u64 ev) { return __builtin_bit_cast(float, (unsigned int)(ev >> 32)); }

// ---------------- CSR build: atomic-free radix (2-level counting sort) ----------------
__global__ __launch_bounds__(256) void k_histA(const int* __restrict__ erow, int* __restrict__ hist) {
    __shared__ int lh[NB1];
    const int t = threadIdx.x, blk = blockIdx.x;
    lh[t] = 0;
    __syncthreads();
    const int base = blk * CHUNK;
    for (int i = t; i < CHUNK; i += 256)
        atomicAdd(&lh[erow[base + i] / RPB1], 1);
    __syncthreads();
    hist[blk * NB1 + t] = lh[t];
}

__global__ __launch_bounds__(256) void k_scanB(const int* __restrict__ hist,
                                               int* __restrict__ offs, int* __restrict__ bucketptr) {
    __shared__ int sd[256];
    const int b = threadIdx.x;
    int run = 0;
#pragma unroll 8
    for (int blk = 0; blk < NBLK; ++blk) {
        int v = hist[blk * NB1 + b];
        offs[blk * NB1 + b] = run;
        run += v;
    }
    sd[b] = run;
    __syncthreads();
    for (int off = 1; off < 256; off <<= 1) {
        int x = (b >= off) ? sd[b - off] : 0;
        __syncthreads();
        sd[b] += x;
        __syncthreads();
    }
    bucketptr[b] = sd[b] - run;
    if (b == 255) bucketptr[NB1] = sd[255];
}

__global__ __launch_bounds__(256) void k_scatC(const int* __restrict__ erow, const int* __restrict__ ecol,
                                               const float* __restrict__ eval_,
                                               const int* __restrict__ offs, const int* __restrict__ bucketptr,
                                               u64* __restrict__ tmp) {
    __shared__ int lbase[NB1];
    __shared__ int lcur[NB1];
    const int t = threadIdx.x, blk = blockIdx.x;
    lbase[t] = bucketptr[t] + offs[blk * NB1 + t];
    lcur[t] = 0;
    __syncthreads();
    const int base = blk * CHUNK;
    for (int i = t; i < CHUNK; i += 256) {
        int r = erow[base + i];
        int c = ecol[base + i];
        unsigned int vb = __builtin_bit_cast(unsigned int, eval_[base + i]);
        int b = r / RPB1;
        int rl = r - b * RPB1;
        int rank = atomicAdd(&lcur[b], 1);
        u64 rec = (u64)((unsigned int)c | ((unsigned int)rl << 17)) | ((u64)vb << 32);
        tmp[lbase[b] + rank] = rec;
    }
}

__global__ __launch_bounds__(512) void k_sortD(const int* __restrict__ bucketptr, const u64* __restrict__ tmp,
                                               u64* __restrict__ pedge, int* __restrict__ rowptr) {
    __shared__ int lcnt[512];
    __shared__ int sc[512];
    __shared__ int lcur[512];
    const int b = blockIdx.x, t = threadIdx.x;
    const int beg = bucketptr[b], end = bucketptr[b + 1];
    const int n = end - beg;
    lcnt[t] = 0;
    __syncthreads();
    for (int i = t; i < n; i += 512)
        atomicAdd(&lcnt[(int)((tmp[beg + i] >> 17) & 0x1ff)], 1);
    __syncthreads();
    sc[t] = lcnt[t];
    __syncthreads();
    for (int off = 1; off < 512; off <<= 1) {
        int x = (t >= off) ? sc[t - off] : 0;
        __syncthreads();
        sc[t] += x;
        __syncthreads();
    }
    int excl = sc[t] - lcnt[t];
    lcur[t] = excl;
    if (t < RPB1) {
        int row = b * RPB1 + t;
        if (row < N_NODES) rowptr[row] = beg + excl;
    }
    if (b == NB1 - 1 && t == 0) rowptr[N_NODES] = N_EDGES;
    __syncthreads();
    for (int i = t; i < n; i += 512) {
        u64 rec = tmp[beg + i];
        int rl = (int)((rec >> 17) & 0x1ff);
        int pos = atomicAdd(&lcur[rl], 1);
        pedge[beg + pos] = rec & 0xFFFFFFFF0001FFFFull;
    }
}

// ---------------- weight transpose + bf16 convert ----------------
__global__ void k_w1t(const float* __restrict__ W1, unsigned short* __restrict__ W1T) {
    int i = blockIdx.x * 256 + threadIdx.x;   // NHID*NFEAT
    int nn = i >> 9, k = i & 511;
    W1T[i] = f2bf(W1[k * NHID + nn]);
}
__global__ void k_w2t(const float* __restrict__ W2, unsigned short* __restrict__ W2T) {
    int i = blockIdx.x * 256 + threadIdx.x;   // 64*NHID
    int nn = i >> 8, k = i & 255;
    W2T[i] = (nn < NCLASS) ? f2bf(W2[k * NCLASS + nn]) : (unsigned short)0;
}

// ---------------- GEMM1: support[row][256] = bf16(x) @ bf16(W1), stored fp8 ----------------
__global__ __launch_bounds__(512) void k_gemm1(const float* __restrict__ X,
                                               const unsigned short* __restrict__ W1T,
                                               unsigned char* __restrict__ support8) {
    __shared__ unsigned short As[128 * LDP];
    __shared__ unsigned short Bs[256 * LDP];
    const int t = threadIdx.x;
    const int lane = t & 63;
    const int w = t >> 6;
    const int wm = w >> 2, wn = w & 3;
    const int l15 = lane & 15, l4 = lane >> 4;
    const int bm = blockIdx.x;

    f32x4 acc[4][4];
#pragma unroll
    for (int m = 0; m < 4; ++m)
#pragma unroll
        for (int n = 0; n < 4; ++n) acc[m][n] = (f32x4){0.f, 0.f, 0.f, 0.f};

    const int arow = t >> 2, aq = t & 3;
    const long growA = (long)bm * 128 + arow;
    const bool avalid = growA < N_NODES;
    const float* xsrc = X + growA * NFEAT + aq * 8;
    unsigned short* adst = &As[arow * LDP + aq * 8];
    const int brow = t >> 1, bhalf = t & 1;
    const unsigned short* bsrc = W1T + (long)brow * NFEAT + bhalf * 16;
    unsigned short* bdst = &Bs[brow * LDP + bhalf * 16];

    for (int kt = 0; kt < NFEAT; kt += 32) {
        union { float4 v4[2]; float f[8]; } a;
        if (avalid) {
            a.v4[0] = *(const float4*)(xsrc + kt + 0);
            a.v4[1] = *(const float4*)(xsrc + kt + 4);
        } else {
            a.v4[0] = make_float4(0.f, 0.f, 0.f, 0.f);
            a.v4[1] = make_float4(0.f, 0.f, 0.f, 0.f);
        }
        union { uint4 q; unsigned short us[8]; } u;
#pragma unroll
        for (int j = 0; j < 8; ++j) u.us[j] = f2bf(a.f[j]);
        uint4 b0 = *(const uint4*)(bsrc + kt);
        uint4 b1v = *(const uint4*)(bsrc + kt + 8);
        *(uint4*)(adst) = u.q;
        *(uint4*)(bdst) = b0;
        *(uint4*)(bdst + 8) = b1v;
        __syncthreads();

        bf16x8 afr[4], bfr[4];
#pragma unroll
        for (int m = 0; m < 4; ++m)
            afr[m] = *(const bf16x8*)&As[(wm * 64 + m * 16 + l15) * LDP + l4 * 8];
#pragma unroll
        for (int n = 0; n < 4; ++n)
            bfr[n] = *(const bf16x8*)&Bs[(wn * 64 + n * 16 + l15) * LDP + l4 * 8];
#pragma unroll
        for (int m = 0; m < 4; ++m)
#pragma unroll
            for (int n = 0; n < 4; ++n)
                acc[m][n] = __builtin_amdgcn_mfma_f32_16x16x32_bf16(bfr[n], afr[m], acc[m][n], 0, 0, 0);
        __syncthreads();
    }
#pragma unroll
    for (int m = 0; m < 4; ++m) {
        long row = (long)bm * 128 + wm * 64 + m * 16 + l15;
        if (row < N_NODES) {
#pragma unroll
            for (int n = 0; n < 4; ++n) {
                int colb = wn * 64 + n * 16 + l4 * 4;
#if SUP_FP8
                int wv = 0;
                wv = __builtin_amdgcn_cvt_pk_fp8_f32(acc[m][n][0], acc[m][n][1], wv, false);
                wv = __builtin_amdgcn_cvt_pk_fp8_f32(acc[m][n][2], acc[m][n][3], wv, true);
                *(unsigned int*)&support8[(size_t)row * NHID + colb] = (unsigned int)wv;
#else
                ushort4 o;
                o.x = f2bf(acc[m][n][0]);
                o.y = f2bf(acc[m][n][1]);
                o.z = f2bf(acc[m][n][2]);
                o.w = f2bf(acc[m][n][3]);
                *(ushort4*)&support8[(size_t)row * NHID * 2 + colb * 2] = o;
#endif
            }
        }
    }
}

// ---------------- SpMM1 + bias + ReLU -> h (bf16). one wave per row, 8-way MLP, fp8 gather ----------------
__global__ __launch_bounds__(256) void k_spmm1(const int* __restrict__ rowptr,
                                               const u64* __restrict__ pedge,
                                               const unsigned char* __restrict__ support8,
                                               const float* __restrict__ b1,
                                               unsigned short* __restrict__ h) {
    int wrow = (blockIdx.x * 256 + threadIdx.x) >> 6;
    int lane = threadIdx.x & 63;
    if (wrow >= N_NODES) return;
    int beg = rowptr[wrow], end = rowptr[wrow + 1];
    float a0 = 0.f, a1 = 0.f, a2 = 0.f, a3 = 0.f;
    const int c4 = lane * 4;
    int e = beg;
#if SUP_FP8
    for (; e + 8 <= end; e += 8) {
        u64 ev[8];
#pragma unroll
        for (int j = 0; j < 8; ++j) ev[j] = __builtin_nontemporal_load(&pedge[e + j]);
        unsigned int g[8];
#pragma unroll
        for (int j = 0; j < 8; ++j)
            g[j] = *(const unsigned int*)&support8[(size_t)ecol_of(ev[j]) * NHID + c4];
#pragma unroll
        for (int j = 0; j < 8; ++j) {
            float v = eval_of(ev[j]);
            f32x2 lo = __builtin_amdgcn_cvt_pk_f32_fp8(g[j], false);
            f32x2 hi = __builtin_amdgcn_cvt_pk_f32_fp8(g[j], true);
            a0 = fmaf(v, lo[0], a0); a1 = fmaf(v, lo[1], a1);
            a2 = fmaf(v, hi[0], a2); a3 = fmaf(v, hi[1], a3);
        }
    }
    for (; e < end; ++e) {
        u64 ev = __builtin_nontemporal_load(&pedge[e]);
        float v = eval_of(ev);
        unsigned int g = *(const unsigned int*)&support8[(size_t)ecol_of(ev) * NHID + c4];
        f32x2 lo = __builtin_amdgcn_cvt_pk_f32_fp8(g, false);
        f32x2 hi = __builtin_amdgcn_cvt_pk_f32_fp8(g, true);
        a0 = fmaf(v, lo[0], a0); a1 = fmaf(v, lo[1], a1);
        a2 = fmaf(v, hi[0], a2); a3 = fmaf(v, hi[1], a3);
    }
#else
    for (; e + 8 <= end; e += 8) {
        u64 ev[8];
#pragma unroll
        for (int j = 0; j < 8; ++j) ev[j] = __builtin_nontemporal_load(&pedge[e + j]);
        uint2 g[8];
#pragma unroll
        for (int j = 0; j < 8; ++j)
            g[j] = *(const uint2*)&support8[((size_t)ecol_of(ev[j]) * NHID + c4) * 2];
#pragma unroll
        for (int j = 0; j < 8; ++j) {
            float v = eval_of(ev[j]);
            a0 = fmaf(v, bflo(g[j].x), a0); a1 = fmaf(v, bfhi(g[j].x), a1);
            a2 = fmaf(v, bflo(g[j].y), a2); a3 = fmaf(v, bfhi(g[j].y), a3);
        }
    }
    for (; e < end; ++e) {
        u64 ev = __builtin_nontemporal_load(&pedge[e]);
        float v = eval_of(ev);
        uint2 g = *(const uint2*)&support8[((size_t)ecol_of(ev) * NHID + c4) * 2];
        a0 = fmaf(v, bflo(g.x), a0); a1 = fmaf(v, bfhi(g.x), a1);
        a2 = fmaf(v, bflo(g.y), a2); a3 = fmaf(v, bfhi(g.y), a3);
    }
#endif
    float4 bb = *(const float4*)&b1[c4];
    a0 = fmaxf(a0 + bb.x, 0.f);
    a1 = fmaxf(a1 + bb.y, 0.f);
    a2 = fmaxf(a2 + bb.z, 0.f);
    a3 = fmaxf(a3 + bb.w, 0.f);
    ushort4 o;
    o.x = f2bf(a0); o.y = f2bf(a1); o.z = f2bf(a2); o.w = f2bf(a3);
    *(ushort4*)&h[(size_t)wrow * NHID + c4] = o;
}

// ---------------- GEMM2: logits2[row][40] = h @ W2 (fp32 out) ----------------
__global__ __launch_bounds__(256) void k_gemm2(const unsigned short* __restrict__ H,
                                               const unsigned short* __restrict__ W2T,
                                               float* __restrict__ logits2) {
    __shared__ unsigned short As[128 * LDP];
    __shared__ unsigned short Bs[64 * LDP];
    const int t = threadIdx.x;
    const int lane = t & 63;
    const int w = t >> 6;
    const int wm = w >> 1, wn = w & 1;
    const int l15 = lane & 15, l4 = lane >> 4;
    const int bm = blockIdx.x;

    f32x4 acc[4][2];
#pragma unroll
    for (int m = 0; m < 4; ++m)
#pragma unroll
        for (int n = 0; n < 2; ++n) acc[m][n] = (f32x4){0.f, 0.f, 0.f, 0.f};

    const int srow = t >> 1, shalf = t & 1;
    const long grow = (long)bm * 128 + srow;
    const bool avalid = grow < N_NODES;
    const unsigned short* asrc = H + grow * NHID + shalf * 16;
    const int bn2 = t >> 2, bq = t & 3;
    const unsigned short* bsrc = W2T + bn2 * NHID + bq * 8;

    for (int kt = 0; kt < NHID; kt += 32) {
        uint4 a0, a1;
        if (avalid) {
            a0 = *(const uint4*)(asrc + kt);
            a1 = *(const uint4*)(asrc + kt + 8);
        } else {
            a0 = make_uint4(0, 0, 0, 0);
            a1 = make_uint4(0, 0, 0, 0);
        }
        uint4 bv = *(const uint4*)(bsrc + kt);
        *(uint4*)&As[srow * LDP + shalf * 16] = a0;
        *(uint4*)&As[srow * LDP + shalf * 16 + 8] = a1;
        *(uint4*)&Bs[bn2 * LDP + bq * 8] = bv;
        __syncthreads();

        bf16x8 afr[4], bfr[2];
#pragma unroll
        for (int m = 0; m < 4; ++m)
            afr[m] = *(const bf16x8*)&As[(wm * 64 + m * 16 + l15) * LDP + l4 * 8];
#pragma unroll
        for (int n = 0; n < 2; ++n)
            bfr[n] = *(const bf16x8*)&Bs[(wn * 32 + n * 16 + l15) * LDP + l4 * 8];
#pragma unroll
        for (int m = 0; m < 4; ++m)
#pragma unroll
            for (int n = 0; n < 2; ++n)
                acc[m][n] = __builtin_amdgcn_mfma_f32_16x16x32_bf16(bfr[n], afr[m], acc[m][n], 0, 0, 0);
        __syncthreads();
    }
#pragma unroll
    for (int m = 0; m < 4; ++m) {
        long row = (long)bm * 128 + wm * 64 + m * 16 + l15;
        if (row < N_NODES) {
#pragma unroll
            for (int n = 0; n < 2; ++n) {
                int colb = wn * 32 + n * 16 + l4 * 4;
                if (colb < NCLASS)
                    *(f32x4*)&logits2[(size_t)row * NCLASS + colb] = acc[m][n];
            }
        }
    }
}

// ---------------- SpMM2 + bias + log_softmax -> out (fp32). one wave per row, 8-way MLP ----------------
__global__ __launch_bounds__(256) void k_spmm2(const int* __restrict__ rowptr,
                                               const u64* __restrict__ pedge,
                                               const float* __restrict__ logits2,
                                               const float* __restrict__ b2, float* __restrict__ out) {
    int wrow = (blockIdx.x * 256 + threadIdx.x) >> 6;
    int lane = threadIdx.x & 63;
    if (wrow >= N_NODES) return;
    int beg = rowptr[wrow], end = rowptr[wrow + 1];
    bool act = lane < NCLASS;
    int colidx = act ? lane : 0;
    float acc = 0.f;
    int e = beg;
    for (; e + 8 <= end; e += 8) {
        u64 ev[8];
#pragma unroll
        for (int j = 0; j < 8; ++j) ev[j] = __builtin_nontemporal_load(&pedge[e + j]);
        float g[8];
#pragma unroll
        for (int j = 0; j < 8; ++j) g[j] = logits2[(size_t)ecol_of(ev[j]) * NCLASS + colidx];
#pragma unroll
        for (int j = 0; j < 8; ++j) acc = fmaf(eval_of(ev[j]), g[j], acc);
    }
    if (e + 4 <= end) {
        u64 ev[4];
#pragma unroll
        for (int j = 0; j < 4; ++j) ev[j] = __builtin_nontemporal_load(&pedge[e + j]);
        float g[4];
#pragma unroll
        for (int j = 0; j < 4; ++j) g[j] = logits2[(size_t)ecol_of(ev[j]) * NCLASS + colidx];
#pragma unroll
        for (int j = 0; j < 4; ++j) acc = fmaf(eval_of(ev[j]), g[j], acc);
        e += 4;
    }
    for (; e < end; ++e) {
        u64 ev = __builtin_nontemporal_load(&pedge[e]);
        float g = logits2[(size_t)ecol_of(ev) * NCLASS + colidx];
        acc = fmaf(eval_of(ev), g, acc);
    }
    acc += b2[colidx];
    float mv = act ? acc : -INFINITY;
#pragma unroll
    for (int off = 32; off; off >>= 1) mv = fmaxf(mv, __shfl_xor(mv, off, 64));
    float p = act ? __expf(acc - mv) : 0.f;
    float s = p;
#pragma unroll
    for (int off = 32; off; off >>= 1) s += __shfl_xor(s, off, 64);
    if (act) out[(size_t)wrow * NCLASS + lane] = acc - mv - __logf(s);
}

extern "C" void kernel_launch(void* const* d_in, const int* in_sizes, int n_in,
                              void* d_out, int out_size, void* d_ws, size_t ws_size,
                              hipStream_t stream) {
    const float* x    = (const float*)d_in[0];
    const int*   erow = (const int*)d_in[1];
    const int*   ecol = (const int*)d_in[2];
    const float* eval_ = (const float*)d_in[3];
    const float* W1   = (const float*)d_in[4];
    const float* b1   = (const float*)d_in[5];
    const float* W2   = (const float*)d_in[6];
    const float* b2   = (const float*)d_in[7];
    float* out = (float*)d_out;

    char* p = (char*)d_ws;
    auto alloc = [&](size_t b) { char* r = p; p += (b + 255) & ~(size_t)255; return r; };
    int* hist              = (int*)alloc((size_t)NBLK * NB1 * 4);
    int* offs              = (int*)alloc((size_t)NBLK * NB1 * 4);
    int* bucketptr         = (int*)alloc((size_t)(NB1 + 1) * 4);
    int* rowptr            = (int*)alloc((size_t)(N_NODES + 1) * 4);
    u64* tmp               = (u64*)alloc((size_t)N_EDGES * 8);
    u64* pedge             = (u64*)alloc((size_t)N_EDGES * 8);
    unsigned short* W1T    = (unsigned short*)alloc((size_t)NHID * NFEAT * 2);
    unsigned short* W2T    = (unsigned short*)alloc((size_t)64 * NHID * 2);
    unsigned char* support8= (unsigned char*)alloc((size_t)N_NODES * NHID * 2); // 2B reserved (bf16 fallback)
    unsigned short* h      = (unsigned short*)alloc((size_t)N_NODES * NHID * 2);
    float* logits2         = (float*)alloc((size_t)N_NODES * NCLASS * 4);

    k_histA<<<NBLK, 256, 0, stream>>>(erow, hist);
    k_scanB<<<1, 256, 0, stream>>>(hist, offs, bucketptr);
    k_scatC<<<NBLK, 256, 0, stream>>>(erow, ecol, eval_, offs, bucketptr, tmp);
    k_sortD<<<NB1, 512, 0, stream>>>(bucketptr, tmp, pedge, rowptr);
    k_w1t<<<(NHID * NFEAT) / 256, 256, 0, stream>>>(W1, W1T);
    k_w2t<<<(64 * NHID) / 256, 256, 0, stream>>>(W2, W2T);
    k_gemm1<<<(N_NODES + 127) / 128, 512, 0, stream>>>(x, W1T, support8);
    k_spmm1<<<(N_NODES + 3) / 4, 256, 0, stream>>>(rowptr, pedge, support8, b1, h);
    k_gemm2<<<(N_NODES + 127) / 128, 256, 0, stream>>>(h, W2T, logits2);
    k_spmm2<<<(N_NODES + 3) / 4, 256, 0, stream>>>(rowptr, pedge, logits2, b2, out);
}